// Round 4
// baseline (363.839 us; speedup 1.0000x reference)
//
#include <hip/hip_runtime.h>
#include <hip/hip_cooperative_groups.h>
#include <stdint.h>

namespace cg = cooperative_groups;

typedef __bf16 bf16x8 __attribute__((ext_vector_type(8)));
typedef float  f32x4  __attribute__((ext_vector_type(4)));

#define E_DIM 1024
#define H_DIM 64
#define T_SEQ 4096
#define B_BAT 4
#define M_TOT (B_BAT * T_SEQ)   // 16384

// f32 -> bf16 via hardware cvt (RNE, v_cvt_pk_bf16_f32). Compiler pairs casts.
__device__ __forceinline__ ushort f2bfu(float f) {
    return __builtin_bit_cast(ushort, (__bf16)f);
}
// packed fp32x2 -> bf16x2 (RNE, single v_cvt_pk_bf16_f32)
__device__ __forceinline__ uint32_t pk2(float lo, float hi) {
    return (uint32_t)f2bfu(lo) | ((uint32_t)f2bfu(hi) << 16);
}
__device__ __forceinline__ float ex2(float x) {    // 2^x, single trans op
    return __builtin_amdgcn_exp2f(x);
}
__device__ __forceinline__ bf16x8 ldfrag(const ushort* p) {
    return __builtin_bit_cast(bf16x8, *(const uint4*)(p));
}
// barrier that waits LDS only — global prefetch stays in flight (vmcnt not drained)
__device__ __forceinline__ void barrier_lgkm() {
    __builtin_amdgcn_s_waitcnt(0xC07F);   // vmcnt(63) expcnt(7) lgkmcnt(0)
    __builtin_amdgcn_s_barrier();
}

// ---------------- single cooperative kernel: wcvt -> qkv -> flash -----------
// 512 blocks x 256 threads = exactly 2 blocks/CU co-resident.
// Phase boundaries are grid.sync() (replaces 2 kernel launch/drain boundaries).
__global__ __launch_bounds__(256, 2) void fused_all(
        const float* __restrict__ x,
        const float* __restrict__ Wq, const float* __restrict__ Wk,
        const float* __restrict__ Wv,
        ushort* __restrict__ Wfm, ushort* __restrict__ Qfm,
        ushort* __restrict__ Kfm, ushort* __restrict__ Vfm,
        float* __restrict__ out) {
    cg::grid_group grid = cg::this_grid();
    __shared__ union {
        ushort a[2][32 * 72];                                    // qkv staging (9216 B)
        struct { ushort c[32 * 136]; ushort vt[64 * 40]; } epi;  // qkv epilogue (13824 B)
        struct { ushort plds[4][16 * 72];                        // flash P (9216 B)
                 float  ro[4][16][68];                           // partial O (17408 B)
                 float  rl[4][16]; } fl;                         // partial l (256 B)
    } sm;

    const int bid = blockIdx.x;
    const int tid = threadIdx.x;
    const int w = tid >> 6, l = tid & 63;
    const int lm = l & 15, qd = l >> 4;

    // ============ phase A: W fp32 -> frag-major bf16 (blocks 0..95) =========
    // Wfm[s 16][nt 12][kc 2][lane 64][8]; Wq rows pre-scaled by 1/(32*ln2)
    // so flash can use exp2 directly.
    if (bid < 96) {
        int g = bid * 256 + tid;   // 24576 workers
        int n = g >> 7;            // 0..191
        int k8 = g & 127;
        const float* src = (n < 64) ? (Wq + (size_t)n * E_DIM)
                         : (n < 128) ? (Wk + (size_t)(n - 64) * E_DIM)
                         : (Wv + (size_t)(n - 128) * E_DIM);
        float sc = (n < 64) ? 0.045084220f : 1.0f;   // (1/32) * (1/ln2)
        float4 a = *(const float4*)(src + k8 * 8);
        float4 b = *(const float4*)(src + k8 * 8 + 4);
        uint4 o;
        o.x = pk2(a.x * sc, a.y * sc); o.y = pk2(a.z * sc, a.w * sc);
        o.z = pk2(b.x * sc, b.y * sc); o.w = pk2(b.z * sc, b.w * sc);
        int s = k8 >> 3, kc = (k8 >> 2) & 1, q4 = k8 & 3;
        int nt = n >> 4, lmn = n & 15;
        int lane = q4 * 16 + lmn;
        *(uint4*)(Wfm + (((size_t)(s * 12 + nt) * 2 + kc) * 64 + lane) * 8) = o;
    }
    __threadfence();
    grid.sync();

    // ============ phase B: QKV projection (all 512 blocks, 32 rows each) ====
    // 3-deep x pipeline (load s+3 / stage s+1 / compute s); lgkm-only in-loop
    // barriers keep global loads in flight.
    {
        const int m0 = bid * 32;

        f32x4 acc[2][3];
#pragma unroll
        for (int r2 = 0; r2 < 2; ++r2)
#pragma unroll
            for (int t = 0; t < 3; ++t) acc[r2][t] = (f32x4){0.f, 0.f, 0.f, 0.f};

        const int srow = tid >> 3, kseg = tid & 7;
        const float* xsrc = x + (size_t)(m0 + srow) * E_DIM + kseg * 8;

        // tile 0 -> LDS[0]
        {
            float4 a0 = *(const float4*)xsrc;
            float4 a1 = *(const float4*)(xsrc + 4);
            uint4 u = {pk2(a0.x, a0.y), pk2(a0.z, a0.w), pk2(a1.x, a1.y), pk2(a1.z, a1.w)};
            *(uint4*)(&sm.a[0][srow * 72 + kseg * 8]) = u;
        }
        // tiles 1,2 -> regs (3-deep pipeline)
        float4 xa0 = *(const float4*)(xsrc + 64);
        float4 xa1 = *(const float4*)(xsrc + 68);
        float4 xb0 = *(const float4*)(xsrc + 128);
        float4 xb1 = *(const float4*)(xsrc + 132);
        __syncthreads();

        for (int s = 0; s < 16; ++s) {
            const int cb = s & 1, nb = cb ^ 1;
            float4 xc0 = xa0, xc1 = xa1;
            if (s < 13) {                       // load tile s+3
                xc0 = *(const float4*)(xsrc + (s + 3) * 64);
                xc1 = *(const float4*)(xsrc + (s + 3) * 64 + 4);
            }
            // W frags for this step (global, L2-resident, lane-dense)
            bf16x8 wf[3][2];
#pragma unroll
            for (int t = 0; t < 3; ++t)
#pragma unroll
                for (int kc = 0; kc < 2; ++kc)
                    wf[t][kc] = ldfrag(Wfm + (((size_t)(s * 12 + w * 3 + t) * 2 + kc) * 64 + l) * 8);
            // A frags from LDS
            bf16x8 af[2][2];
#pragma unroll
            for (int r2 = 0; r2 < 2; ++r2)
#pragma unroll
                for (int kc = 0; kc < 2; ++kc)
                    af[r2][kc] = ldfrag(&sm.a[cb][(r2 * 16 + lm) * 72 + kc * 32 + qd * 8]);
#pragma unroll
            for (int t = 0; t < 3; ++t)
#pragma unroll
                for (int kc = 0; kc < 2; ++kc)
#pragma unroll
                    for (int r2 = 0; r2 < 2; ++r2)
                        acc[r2][t] = __builtin_amdgcn_mfma_f32_16x16x32_bf16(af[r2][kc], wf[t][kc], acc[r2][t], 0, 0, 0);
            // stage tile s+1 (regs loaded two full steps ago)
            if (s < 15) {
                uint4 u = {pk2(xa0.x, xa0.y), pk2(xa0.z, xa0.w), pk2(xa1.x, xa1.y), pk2(xa1.z, xa1.w)};
                *(uint4*)(&sm.a[nb][srow * 72 + kseg * 8]) = u;
            }
            xa0 = xb0; xa1 = xb1; xb0 = xc0; xb1 = xc1;
            if (s < 15) barrier_lgkm();
        }
        __syncthreads();

        // epilogue: acc -> LDS transpose -> frag-major dense stores
#pragma unroll
        for (int r2 = 0; r2 < 2; ++r2)
#pragma unroll
            for (int t = 0; t < 3; ++t) {
                int gc = w * 48 + t * 16 + lm;
                int m = r2 * 16 + qd * 4;
#pragma unroll
                for (int rr = 0; rr < 4; ++rr) {
                    ushort v = f2bfu(acc[r2][t][rr]);
                    if (gc < 128) sm.epi.c[(m + rr) * 136 + gc] = v;
                    else          sm.epi.vt[(gc - 128) * 40 + (m + rr)] = v;
                }
            }
        __syncthreads();

        const int g16b = m0 >> 4;
        const int kt64 = m0 >> 6;
        const int tb   = (m0 >> 4) & 3;
        const int kcv  = (m0 >> 5) & 1;
#pragma unroll
        for (int ii = 0; ii < 3; ++ii) {
            int i = w + ii * 4;
            uint4 val;
            ushort* dst;
            if (i < 4) {
                int qt_l = i >> 1, kc = i & 1;
                val = *(const uint4*)(&sm.epi.c[(qt_l * 16 + lm) * 136 + kc * 32 + qd * 8]);
                dst = Qfm + (((size_t)(g16b + qt_l) * 2 + kc) * 64 + l) * 8;
            } else if (i < 8) {
                int j2 = i - 4, t_l = j2 >> 1, kc = j2 & 1;
                val = *(const uint4*)(&sm.epi.c[(t_l * 16 + lm) * 136 + 64 + kc * 32 + qd * 8]);
                dst = Kfm + (((size_t)((kt64 * 4 + tb + t_l) * 2 + kc)) * 64 + l) * 8;
            } else {
                int t = i - 8;
                val = *(const uint4*)(&sm.epi.vt[(t * 16 + lm) * 40 + qd * 8]);
                dst = Vfm + (((size_t)((kt64 * 4 + t) * 2 + kcv)) * 64 + l) * 8;
            }
            *(uint4*)dst = val;
        }
    }
    __threadfence();
    grid.sync();

    // ============ phase C: causal flash attention, fused split-K ============
    // bt = bid & 3 so each XCD's resident blocks share one batch's K/V
    // (2 MB < 4 MB XCD-L2 under the round-robin bid->XCD mapping).
    {
        const int pr = bid >> 2;     // pair 0..127
        const int bt = bid & 3;
        const int wv = w;
        ushort* myp = sm.fl.plds[wv];

#pragma unroll 1
        for (int half = 0; half < 2; ++half) {
            const int j   = half ? (255 - pr) : pr;   // q-16-row tile 0..255
            const int ktd = j >> 2;                   // diagonal 64-key tile
            const int td  = j & 3;                    // diagonal 16-key subtile
            const int g16 = bt * 256 + j;

            bf16x8 qf0, qf1;
            {
                const ushort* qp = Qfm + ((size_t)g16 * 2) * 512 + l * 8;
                qf0 = ldfrag(qp);
                qf1 = ldfrag(qp + 512);
            }
            f32x4 o[4];
#pragma unroll
            for (int t = 0; t < 4; ++t) o[t] = (f32x4){0.f, 0.f, 0.f, 0.f};
            float lacc = 0.f;

#pragma unroll 1
            for (int kt = wv; kt <= ktd; kt += 4) {
                const ushort* kb = Kfm + ((size_t)(bt * 64 + kt) * 8) * 512;
                const ushort* vb = Vfm + ((size_t)(bt * 64 + kt) * 8) * 512;
                f32x4 sf[4];
#pragma unroll
                for (int t = 0; t < 4; ++t) sf[t] = (f32x4){0.f, 0.f, 0.f, 0.f};
#pragma unroll
                for (int t = 0; t < 4; ++t) {
                    bf16x8 k0 = ldfrag(kb + (t * 2 + 0) * 512 + l * 8);
                    bf16x8 k1 = ldfrag(kb + (t * 2 + 1) * 512 + l * 8);
                    sf[t] = __builtin_amdgcn_mfma_f32_16x16x32_bf16(k0, qf0, sf[t], 0, 0, 0);
                    sf[t] = __builtin_amdgcn_mfma_f32_16x16x32_bf16(k1, qf1, sf[t], 0, 0, 0);
                }
                uint4 vu[4][2];
#pragma unroll
                for (int t = 0; t < 4; ++t) {
                    vu[t][0] = *(const uint4*)(vb + (t * 2 + 0) * 512 + l * 8);
                    vu[t][1] = *(const uint4*)(vb + (t * 2 + 1) * 512 + l * 8);
                }
                ushort* wp = myp + lm * 72 + qd * 4;
                if (kt != ktd) {           // fully unmasked tile
#pragma unroll
                    for (int t = 0; t < 4; ++t) {
                        float p0 = ex2(sf[t][0]), p1 = ex2(sf[t][1]);
                        float p2 = ex2(sf[t][2]), p3 = ex2(sf[t][3]);
                        lacc += (p0 + p1) + (p2 + p3);
                        *(uint2*)(wp + t * 16) = uint2{pk2(p0, p1), pk2(p2, p3)};
                    }
                } else {                   // diagonal: t<td full, t==td tri, t>td zero
#pragma unroll
                    for (int t = 0; t < 4; ++t) {
                        if (t < td) {
                            float p0 = ex2(sf[t][0]), p1 = ex2(sf[t][1]);
                            float p2 = ex2(sf[t][2]), p3 = ex2(sf[t][3]);
                            lacc += (p0 + p1) + (p2 + p3);
                            *(uint2*)(wp + t * 16) = uint2{pk2(p0, p1), pk2(p2, p3)};
                        } else if (t == td) {
                            float p[4];
#pragma unroll
                            for (int rr = 0; rr < 4; ++rr) {
                                float pe = ex2(sf[t][rr]);
                                if (qd * 4 + rr > lm) pe = 0.f;
                                lacc += pe;
                                p[rr] = pe;
                            }
                            *(uint2*)(wp + t * 16) = uint2{pk2(p[0], p[1]), pk2(p[2], p[3])};
                        } else {
                            *(uint2*)(wp + t * 16) = uint2{0u, 0u};
                        }
                    }
                }
                __builtin_amdgcn_wave_barrier();
                __builtin_amdgcn_s_waitcnt(0xC07F);  // lgkmcnt(0): P committed (wave-private)
                __builtin_amdgcn_wave_barrier();
                bf16x8 pf0 = ldfrag(myp + lm * 72 + qd * 8);
                bf16x8 pf1 = ldfrag(myp + lm * 72 + 32 + qd * 8);
#pragma unroll
                for (int t = 0; t < 4; ++t) {
                    bf16x8 v0 = __builtin_bit_cast(bf16x8, vu[t][0]);
                    bf16x8 v1 = __builtin_bit_cast(bf16x8, vu[t][1]);
                    o[t] = __builtin_amdgcn_mfma_f32_16x16x32_bf16(pf0, v0, o[t], 0, 0, 0);
                    o[t] = __builtin_amdgcn_mfma_f32_16x16x32_bf16(pf1, v1, o[t], 0, 0, 0);
                }
                __builtin_amdgcn_wave_barrier();  // next iter's P writes stay after reads
            }
            // per-wave l for each query row
            lacc += __shfl_xor(lacc, 16);
            lacc += __shfl_xor(lacc, 32);
            if (qd == 0) sm.fl.rl[wv][lm] = lacc;
            // partial O tile -> LDS (row stride 68: 2-way bank alias, free)
#pragma unroll
            for (int t = 0; t < 4; ++t)
#pragma unroll
                for (int rr = 0; rr < 4; ++rr)
                    sm.fl.ro[wv][qd * 4 + rr][t * 16 + lm] = o[t][rr];
            __syncthreads();
            // cross-wave reduce: wave wv sums rows [4wv, 4wv+4), writes final out
            {
                const int row = wv * 4 + qd;
                float ls = sm.fl.rl[0][row] + sm.fl.rl[1][row] + sm.fl.rl[2][row] + sm.fl.rl[3][row];
                float inv = 1.0f / ls;
                float4 s0 = *(const float4*)&sm.fl.ro[0][row][lm * 4];
                float4 s1 = *(const float4*)&sm.fl.ro[1][row][lm * 4];
                float4 s2 = *(const float4*)&sm.fl.ro[2][row][lm * 4];
                float4 s3 = *(const float4*)&sm.fl.ro[3][row][lm * 4];
                float4 ov;
                ov.x = (s0.x + s1.x + s2.x + s3.x) * inv;
                ov.y = (s0.y + s1.y + s2.y + s3.y) * inv;
                ov.z = (s0.z + s1.z + s2.z + s3.z) * inv;
                ov.w = (s0.w + s1.w + s2.w + s3.w) * inv;
                *(float4*)(out + ((size_t)bt * T_SEQ + j * 16 + row) * 64 + lm * 4) = ov;
            }
            __syncthreads();   // protect ro/rl before next half's writes
        }
    }
}

extern "C" void kernel_launch(void* const* d_in, const int* in_sizes, int n_in,
                              void* d_out, int out_size, void* d_ws, size_t ws_size,
                              hipStream_t stream) {
    const float* x  = (const float*)d_in[0];
    const float* Wq = (const float*)d_in[1];
    const float* Wk = (const float*)d_in[2];
    const float* Wv = (const float*)d_in[3];
    float* out = (float*)d_out;

    char* ws = (char*)d_ws;
    ushort* Wfm = (ushort*)(ws);                 // 384 KB
    ushort* Qfm = (ushort*)(ws + 393216);        // 2 MB
    ushort* Kfm = (ushort*)(ws + 2490368);       // 2 MB
    ushort* Vfm = (ushort*)(ws + 4587520);       // 2 MB

    void* args[] = { (void*)&x, (void*)&Wq, (void*)&Wk, (void*)&Wv,
                     (void*)&Wfm, (void*)&Qfm, (void*)&Kfm, (void*)&Vfm,
                     (void*)&out };
    hipLaunchCooperativeKernel((const void*)fused_all, dim3(512), dim3(256),
                               args, 0, stream);
}

// Round 5
// 132.814 us; speedup vs baseline: 2.7395x; 2.7395x over previous
//
#include <hip/hip_runtime.h>
#include <stdint.h>

typedef __bf16 bf16x8 __attribute__((ext_vector_type(8)));
typedef float  f32x4  __attribute__((ext_vector_type(4)));

#define E_DIM 1024
#define H_DIM 64
#define T_SEQ 4096
#define B_BAT 4
#define M_TOT (B_BAT * T_SEQ)   // 16384

// f32 -> bf16 via hardware cvt (RNE, v_cvt_pk_bf16_f32). Compiler pairs casts.
__device__ __forceinline__ ushort f2bfu(float f) {
    return __builtin_bit_cast(ushort, (__bf16)f);
}
// packed fp32x2 -> bf16x2 (RNE, single v_cvt_pk_bf16_f32)
__device__ __forceinline__ uint32_t pk2(float lo, float hi) {
    return (uint32_t)f2bfu(lo) | ((uint32_t)f2bfu(hi) << 16);
}
__device__ __forceinline__ float ex2(float x) {    // 2^x, single trans op
    return __builtin_amdgcn_exp2f(x);
}
__device__ __forceinline__ bf16x8 ldfrag(const ushort* p) {
    return __builtin_bit_cast(bf16x8, *(const uint4*)(p));
}
// barrier that waits LDS only — global prefetch stays in flight (vmcnt not drained)
__device__ __forceinline__ void barrier_lgkm() {
    __builtin_amdgcn_s_waitcnt(0xC07F);   // vmcnt(63) expcnt(7) lgkmcnt(0)
    __builtin_amdgcn_s_barrier();
}

// ---------------- kernel 0: W fp32 -> frag-major bf16 -----------------------
// Wfm[s 16][nt 12][kc 2][lane 64][8]; Wq rows (n<64) pre-scaled by 1/(32*ln2)
// so flash can use exp2 directly (softmax invariant to the log-base change).
__global__ __launch_bounds__(256) void wcvt(const float* __restrict__ Wq,
                                            const float* __restrict__ Wk,
                                            const float* __restrict__ Wv,
                                            ushort* __restrict__ Wfm) {
    int g = blockIdx.x * 256 + threadIdx.x;   // 24576 threads
    int n = g >> 7;          // 0..191
    int k8 = g & 127;
    const float* src = (n < 64) ? (Wq + (size_t)n * E_DIM)
                     : (n < 128) ? (Wk + (size_t)(n - 64) * E_DIM)
                     : (Wv + (size_t)(n - 128) * E_DIM);
    float sc = (n < 64) ? 0.045084220f : 1.0f;   // (1/32) * (1/ln2)
    float4 a = *(const float4*)(src + k8 * 8);
    float4 b = *(const float4*)(src + k8 * 8 + 4);
    uint4 o;
    o.x = pk2(a.x * sc, a.y * sc); o.y = pk2(a.z * sc, a.w * sc);
    o.z = pk2(b.x * sc, b.y * sc); o.w = pk2(b.z * sc, b.w * sc);
    int s = k8 >> 3, kc = (k8 >> 2) & 1, qd = k8 & 3;
    int nt = n >> 4, lm = n & 15;
    int lane = qd * 16 + lm;
    *(uint4*)(Wfm + (((size_t)(s * 12 + nt) * 2 + kc) * 64 + lane) * 8) = o;
}

// ---------------- kernel 1: QKV projection ----------------------------------
// 32-row blocks, BK=64, 16 steps. 3-deep x pipeline (load s+3 / stage s+1 /
// compute s); lgkm-only in-loop barriers keep global loads in flight.
__global__ __launch_bounds__(256, 3) void qkv(const float* __restrict__ x,
                                              const ushort* __restrict__ Wfm,
                                              ushort* __restrict__ Qfm,
                                              ushort* __restrict__ Kfm,
                                              ushort* __restrict__ Vfm) {
    __shared__ union {
        ushort a[2][32 * 72];                              // staging dbuf (9216 B)
        struct { ushort c[32 * 136]; ushort vt[64 * 40]; } epi;  // epilogue (13824 B)
    } sm;
    const int tid = threadIdx.x;
    const int w = tid >> 6, l = tid & 63;
    const int lm = l & 15, qd = l >> 4;
    const int m0 = blockIdx.x * 32;

    f32x4 acc[2][3];
#pragma unroll
    for (int r2 = 0; r2 < 2; ++r2)
#pragma unroll
        for (int t = 0; t < 3; ++t) acc[r2][t] = (f32x4){0.f, 0.f, 0.f, 0.f};

    const int srow = tid >> 3, kseg = tid & 7;
    const float* xsrc = x + (size_t)(m0 + srow) * E_DIM + kseg * 8;

    // tile 0 -> LDS[0]
    {
        float4 a0 = *(const float4*)xsrc;
        float4 a1 = *(const float4*)(xsrc + 4);
        uint4 u = {pk2(a0.x, a0.y), pk2(a0.z, a0.w), pk2(a1.x, a1.y), pk2(a1.z, a1.w)};
        *(uint4*)(&sm.a[0][srow * 72 + kseg * 8]) = u;
    }
    // tiles 1,2 -> regs (3-deep pipeline)
    float4 xa0 = *(const float4*)(xsrc + 64);
    float4 xa1 = *(const float4*)(xsrc + 68);
    float4 xb0 = *(const float4*)(xsrc + 128);
    float4 xb1 = *(const float4*)(xsrc + 132);
    __syncthreads();

    for (int s = 0; s < 16; ++s) {
        const int cb = s & 1, nb = cb ^ 1;
        float4 xc0 = xa0, xc1 = xa1;
        if (s < 13) {                       // load tile s+3
            xc0 = *(const float4*)(xsrc + (s + 3) * 64);
            xc1 = *(const float4*)(xsrc + (s + 3) * 64 + 4);
        }
        // W frags for this step (global, L2-resident, lane-dense)
        bf16x8 wf[3][2];
#pragma unroll
        for (int t = 0; t < 3; ++t)
#pragma unroll
            for (int kc = 0; kc < 2; ++kc)
                wf[t][kc] = ldfrag(Wfm + (((size_t)(s * 12 + w * 3 + t) * 2 + kc) * 64 + l) * 8);
        // A frags from LDS
        bf16x8 af[2][2];
#pragma unroll
        for (int r2 = 0; r2 < 2; ++r2)
#pragma unroll
            for (int kc = 0; kc < 2; ++kc)
                af[r2][kc] = ldfrag(&sm.a[cb][(r2 * 16 + lm) * 72 + kc * 32 + qd * 8]);
#pragma unroll
        for (int t = 0; t < 3; ++t)
#pragma unroll
            for (int kc = 0; kc < 2; ++kc)
#pragma unroll
                for (int r2 = 0; r2 < 2; ++r2)
                    acc[r2][t] = __builtin_amdgcn_mfma_f32_16x16x32_bf16(af[r2][kc], wf[t][kc], acc[r2][t], 0, 0, 0);
        // stage tile s+1 (regs loaded two full steps ago)
        if (s < 15) {
            uint4 u = {pk2(xa0.x, xa0.y), pk2(xa0.z, xa0.w), pk2(xa1.x, xa1.y), pk2(xa1.z, xa1.w)};
            *(uint4*)(&sm.a[nb][srow * 72 + kseg * 8]) = u;
        }
        xa0 = xb0; xa1 = xb1; xb0 = xc0; xb1 = xc1;
        if (s < 15) barrier_lgkm();
    }
    __syncthreads();

    // epilogue: acc -> LDS transpose -> frag-major dense stores
#pragma unroll
    for (int r2 = 0; r2 < 2; ++r2)
#pragma unroll
        for (int t = 0; t < 3; ++t) {
            int gc = w * 48 + t * 16 + lm;
            int m = r2 * 16 + qd * 4;
#pragma unroll
            for (int rr = 0; rr < 4; ++rr) {
                ushort v = f2bfu(acc[r2][t][rr]);
                if (gc < 128) sm.epi.c[(m + rr) * 136 + gc] = v;
                else          sm.epi.vt[(gc - 128) * 40 + (m + rr)] = v;
            }
        }
    __syncthreads();

    const int g16b = m0 >> 4;
    const int kt64 = m0 >> 6;
    const int tb   = (m0 >> 4) & 3;
    const int kcv  = (m0 >> 5) & 1;
#pragma unroll
    for (int ii = 0; ii < 3; ++ii) {
        int i = w + ii * 4;
        uint4 val;
        ushort* dst;
        if (i < 4) {
            int qt_l = i >> 1, kc = i & 1;
            val = *(const uint4*)(&sm.epi.c[(qt_l * 16 + lm) * 136 + kc * 32 + qd * 8]);
            dst = Qfm + (((size_t)(g16b + qt_l) * 2 + kc) * 64 + l) * 8;
        } else if (i < 8) {
            int j2 = i - 4, t_l = j2 >> 1, kc = j2 & 1;
            val = *(const uint4*)(&sm.epi.c[(t_l * 16 + lm) * 136 + 64 + kc * 32 + qd * 8]);
            dst = Kfm + (((size_t)((kt64 * 4 + tb + t_l) * 2 + kc)) * 64 + l) * 8;
        } else {
            int t = i - 8;
            val = *(const uint4*)(&sm.epi.vt[(t * 16 + lm) * 40 + qd * 8]);
            dst = Vfm + (((size_t)((kt64 * 4 + t) * 2 + kcv)) * 64 + l) * 8;
        }
        *(uint4*)dst = val;
    }
}

// ---------------- kernel 2: causal flash attention, merged pair -------------
// Each wave processes q-tiles jA=pr (0..127) and jB=255-pr (128..255)
// SIMULTANEOUSLY, sharing every K/V fragment load. Loop 1 (kt<=ktdA): one
// K/V load feeds both tiles (16 MFMA/load); loop 2: B only. ktdA<32<=ktdB
// always, so the split is exact. 4 waves split keys; LDS block-reduce at end.
__global__ __launch_bounds__(256, 2) void flashm(const ushort* __restrict__ Qfm,
                                                 const ushort* __restrict__ Kfm,
                                                 const ushort* __restrict__ Vfm,
                                                 float* __restrict__ out) {
    __shared__ union {
        ushort plds[4][2][16 * 72];                       // per wave, per tile (18432 B)
        struct { float ro[4][16][68]; float rl[4][16]; } red;  // block reduce (17664 B)
    } sm;
    const int tid = threadIdx.x;
    const int wv = tid >> 6, l = tid & 63;
    const int lm = l & 15, qd = l >> 4;
    const int pr = blockIdx.x;   // 0..127
    const int bt = blockIdx.y;
    const int jA = pr, jB = 255 - pr;
    const int ktdA = jA >> 2, tdA = jA & 3;
    const int ktdB = jB >> 2, tdB = jB & 3;
    ushort* mypA = sm.plds[wv][0];
    ushort* mypB = sm.plds[wv][1];

    bf16x8 qA0, qA1, qB0, qB1;
    {
        const ushort* qp = Qfm + ((size_t)(bt * 256 + jA) * 2) * 512 + l * 8;
        qA0 = ldfrag(qp); qA1 = ldfrag(qp + 512);
        const ushort* qq = Qfm + ((size_t)(bt * 256 + jB) * 2) * 512 + l * 8;
        qB0 = ldfrag(qq); qB1 = ldfrag(qq + 512);
    }
    f32x4 oA[4], oB[4];
#pragma unroll
    for (int t = 0; t < 4; ++t) {
        oA[t] = (f32x4){0.f, 0.f, 0.f, 0.f};
        oB[t] = (f32x4){0.f, 0.f, 0.f, 0.f};
    }
    float laccA = 0.f, laccB = 0.f;

    // P emission: exp2 + pack to LDS; diag => causal subtile masking
    auto emitP = [&](const f32x4* sf, ushort* wp, bool diag, int td, float& lacc) {
#pragma unroll
        for (int t = 0; t < 4; ++t) {
            if (!diag || t < td) {
                float p0 = ex2(sf[t][0]), p1 = ex2(sf[t][1]);
                float p2 = ex2(sf[t][2]), p3 = ex2(sf[t][3]);
                lacc += (p0 + p1) + (p2 + p3);
                *(uint2*)(wp + t * 16) = uint2{pk2(p0, p1), pk2(p2, p3)};
            } else if (t == td) {
                float p[4];
#pragma unroll
                for (int rr = 0; rr < 4; ++rr) {
                    float pe = ex2(sf[t][rr]);
                    if (qd * 4 + rr > lm) pe = 0.f;
                    lacc += pe;
                    p[rr] = pe;
                }
                *(uint2*)(wp + t * 16) = uint2{pk2(p[0], p[1]), pk2(p[2], p[3])};
            } else {
                *(uint2*)(wp + t * 16) = uint2{0u, 0u};
            }
        }
    };
    auto pv = [&](const ushort* myp, const uint4 (&vu)[4][2], f32x4* o) {
        bf16x8 p0 = ldfrag(myp + lm * 72 + qd * 8);
        bf16x8 p1 = ldfrag(myp + lm * 72 + 32 + qd * 8);
#pragma unroll
        for (int t = 0; t < 4; ++t) {
            bf16x8 v0 = __builtin_bit_cast(bf16x8, vu[t][0]);
            bf16x8 v1 = __builtin_bit_cast(bf16x8, vu[t][1]);
            o[t] = __builtin_amdgcn_mfma_f32_16x16x32_bf16(p0, v0, o[t], 0, 0, 0);
            o[t] = __builtin_amdgcn_mfma_f32_16x16x32_bf16(p1, v1, o[t], 0, 0, 0);
        }
    };

    int kt = wv;
    // ---- loop 1: both tiles active; K/V loads shared ----
#pragma unroll 1
    for (; kt <= ktdA; kt += 4) {
        const ushort* kb = Kfm + ((size_t)(bt * 64 + kt) * 8) * 512;
        const ushort* vb = Vfm + ((size_t)(bt * 64 + kt) * 8) * 512;
        f32x4 sfA[4], sfB[4];
#pragma unroll
        for (int t = 0; t < 4; ++t) {
            sfA[t] = (f32x4){0.f, 0.f, 0.f, 0.f};
            sfB[t] = (f32x4){0.f, 0.f, 0.f, 0.f};
        }
#pragma unroll
        for (int t = 0; t < 4; ++t) {
            bf16x8 k0 = ldfrag(kb + (t * 2 + 0) * 512 + l * 8);
            bf16x8 k1 = ldfrag(kb + (t * 2 + 1) * 512 + l * 8);
            sfB[t] = __builtin_amdgcn_mfma_f32_16x16x32_bf16(k0, qB0, sfB[t], 0, 0, 0);
            sfB[t] = __builtin_amdgcn_mfma_f32_16x16x32_bf16(k1, qB1, sfB[t], 0, 0, 0);
            sfA[t] = __builtin_amdgcn_mfma_f32_16x16x32_bf16(k0, qA0, sfA[t], 0, 0, 0);
            sfA[t] = __builtin_amdgcn_mfma_f32_16x16x32_bf16(k1, qA1, sfA[t], 0, 0, 0);
        }
        uint4 vu[4][2];
#pragma unroll
        for (int t = 0; t < 4; ++t) {
            vu[t][0] = *(const uint4*)(vb + (t * 2 + 0) * 512 + l * 8);
            vu[t][1] = *(const uint4*)(vb + (t * 2 + 1) * 512 + l * 8);
        }
        emitP(sfB, mypB + lm * 72 + qd * 4, false, tdB, laccB);       // kt < ktdB always here
        emitP(sfA, mypA + lm * 72 + qd * 4, kt == ktdA, tdA, laccA);
        __builtin_amdgcn_wave_barrier();
        __builtin_amdgcn_s_waitcnt(0xC07F);  // lgkmcnt(0): P committed (wave-private)
        __builtin_amdgcn_wave_barrier();
        pv(mypB, vu, oB);
        pv(mypA, vu, oA);
        __builtin_amdgcn_wave_barrier();     // next iter's P writes stay after reads
    }
    // ---- loop 2: tile B only ----
#pragma unroll 1
    for (; kt <= ktdB; kt += 4) {
        const ushort* kb = Kfm + ((size_t)(bt * 64 + kt) * 8) * 512;
        const ushort* vb = Vfm + ((size_t)(bt * 64 + kt) * 8) * 512;
        f32x4 sfB[4];
#pragma unroll
        for (int t = 0; t < 4; ++t) sfB[t] = (f32x4){0.f, 0.f, 0.f, 0.f};
#pragma unroll
        for (int t = 0; t < 4; ++t) {
            bf16x8 k0 = ldfrag(kb + (t * 2 + 0) * 512 + l * 8);
            bf16x8 k1 = ldfrag(kb + (t * 2 + 1) * 512 + l * 8);
            sfB[t] = __builtin_amdgcn_mfma_f32_16x16x32_bf16(k0, qB0, sfB[t], 0, 0, 0);
            sfB[t] = __builtin_amdgcn_mfma_f32_16x16x32_bf16(k1, qB1, sfB[t], 0, 0, 0);
        }
        uint4 vu[4][2];
#pragma unroll
        for (int t = 0; t < 4; ++t) {
            vu[t][0] = *(const uint4*)(vb + (t * 2 + 0) * 512 + l * 8);
            vu[t][1] = *(const uint4*)(vb + (t * 2 + 1) * 512 + l * 8);
        }
        emitP(sfB, mypB + lm * 72 + qd * 4, kt == ktdB, tdB, laccB);
        __builtin_amdgcn_wave_barrier();
        __builtin_amdgcn_s_waitcnt(0xC07F);
        __builtin_amdgcn_wave_barrier();
        pv(mypB, vu, oB);
        __builtin_amdgcn_wave_barrier();
    }

    // per-wave l for each query row (all lanes hold it after xor-reduce)
    laccA += __shfl_xor(laccA, 16); laccA += __shfl_xor(laccA, 32);
    laccB += __shfl_xor(laccB, 16); laccB += __shfl_xor(laccB, 32);

    __syncthreads();   // all waves done with plds -> safe to reuse as red
    // ---- tile A block-reduce + store ----
    if (qd == 0) sm.red.rl[wv][lm] = laccA;
#pragma unroll
    for (int t = 0; t < 4; ++t)
#pragma unroll
        for (int rr = 0; rr < 4; ++rr)
            sm.red.ro[wv][qd * 4 + rr][t * 16 + lm] = oA[t][rr];
    __syncthreads();
    {
        const int row = wv * 4 + qd;
        float ls = sm.red.rl[0][row] + sm.red.rl[1][row] + sm.red.rl[2][row] + sm.red.rl[3][row];
        float inv = 1.0f / ls;
        float4 s0 = *(const float4*)&sm.red.ro[0][row][lm * 4];
        float4 s1 = *(const float4*)&sm.red.ro[1][row][lm * 4];
        float4 s2 = *(const float4*)&sm.red.ro[2][row][lm * 4];
        float4 s3 = *(const float4*)&sm.red.ro[3][row][lm * 4];
        float4 ov;
        ov.x = (s0.x + s1.x + s2.x + s3.x) * inv;
        ov.y = (s0.y + s1.y + s2.y + s3.y) * inv;
        ov.z = (s0.z + s1.z + s2.z + s3.z) * inv;
        ov.w = (s0.w + s1.w + s2.w + s3.w) * inv;
        *(float4*)(out + ((size_t)bt * T_SEQ + jA * 16 + row) * 64 + lm * 4) = ov;
    }
    __syncthreads();
    // ---- tile B block-reduce + store ----
    if (qd == 0) sm.red.rl[wv][lm] = laccB;
#pragma unroll
    for (int t = 0; t < 4; ++t)
#pragma unroll
        for (int rr = 0; rr < 4; ++rr)
            sm.red.ro[wv][qd * 4 + rr][t * 16 + lm] = oB[t][rr];
    __syncthreads();
    {
        const int row = wv * 4 + qd;
        float ls = sm.red.rl[0][row] + sm.red.rl[1][row] + sm.red.rl[2][row] + sm.red.rl[3][row];
        float inv = 1.0f / ls;
        float4 s0 = *(const float4*)&sm.red.ro[0][row][lm * 4];
        float4 s1 = *(const float4*)&sm.red.ro[1][row][lm * 4];
        float4 s2 = *(const float4*)&sm.red.ro[2][row][lm * 4];
        float4 s3 = *(const float4*)&sm.red.ro[3][row][lm * 4];
        float4 ov;
        ov.x = (s0.x + s1.x + s2.x + s3.x) * inv;
        ov.y = (s0.y + s1.y + s2.y + s3.y) * inv;
        ov.z = (s0.z + s1.z + s2.z + s3.z) * inv;
        ov.w = (s0.w + s1.w + s2.w + s3.w) * inv;
        *(float4*)(out + ((size_t)bt * T_SEQ + jB * 16 + row) * 64 + lm * 4) = ov;
    }
}

extern "C" void kernel_launch(void* const* d_in, const int* in_sizes, int n_in,
                              void* d_out, int out_size, void* d_ws, size_t ws_size,
                              hipStream_t stream) {
    const float* x  = (const float*)d_in[0];
    const float* Wq = (const float*)d_in[1];
    const float* Wk = (const float*)d_in[2];
    const float* Wv = (const float*)d_in[3];
    float* out = (float*)d_out;

    char* ws = (char*)d_ws;
    ushort* Wfm = (ushort*)(ws);                 // 384 KB
    ushort* Qfm = (ushort*)(ws + 393216);        // 2 MB
    ushort* Kfm = (ushort*)(ws + 2490368);       // 2 MB
    ushort* Vfm = (ushort*)(ws + 4587520);       // 2 MB

    wcvt<<<96, 256, 0, stream>>>(Wq, Wk, Wv, Wfm);
    qkv<<<512, 256, 0, stream>>>(x, Wfm, Qfm, Kfm, Vfm);
    flashm<<<dim3(128, B_BAT), 256, 0, stream>>>(Qfm, Kfm, Vfm, out);
}

// Round 8
// 131.586 us; speedup vs baseline: 2.7650x; 1.0093x over previous
//
#include <hip/hip_runtime.h>
#include <stdint.h>

typedef __bf16 bf16x8 __attribute__((ext_vector_type(8)));
typedef float  f32x4  __attribute__((ext_vector_type(4)));

#define E_DIM 1024
#define H_DIM 64
#define T_SEQ 4096
#define B_BAT 4
#define M_TOT (B_BAT * T_SEQ)   // 16384

// f32 -> bf16 via hardware cvt (RNE, v_cvt_pk_bf16_f32). Compiler pairs casts.
__device__ __forceinline__ ushort f2bfu(float f) {
    return __builtin_bit_cast(ushort, (__bf16)f);
}
// packed fp32x2 -> bf16x2 (RNE, single v_cvt_pk_bf16_f32)
__device__ __forceinline__ uint32_t pk2(float lo, float hi) {
    return (uint32_t)f2bfu(lo) | ((uint32_t)f2bfu(hi) << 16);
}
__device__ __forceinline__ float ex2(float x) {    // 2^x, single trans op
    return __builtin_amdgcn_exp2f(x);
}
__device__ __forceinline__ bf16x8 ldfrag(const ushort* p) {
    return __builtin_bit_cast(bf16x8, *(const uint4*)(p));
}
// barrier that waits LDS only — global prefetch stays in flight (vmcnt not drained)
__device__ __forceinline__ void barrier_lgkm() {
    __builtin_amdgcn_s_waitcnt(0xC07F);   // vmcnt(63) expcnt(7) lgkmcnt(0)
    __builtin_amdgcn_s_barrier();
}

// ---------------- kernel 0: W fp32 -> frag-major bf16 -----------------------
// Wfm[s 16][nt 12][kc 2][lane 64][8]; Wq rows (n<64) pre-scaled by 1/(32*ln2)
// so flash can use exp2 directly (softmax invariant to the log-base change).
// NOTE (R6 lesson): keep as a separate kernel — inter-block flag spins
// deadlock under this harness; launch boundaries cost only ~1-2 us.
__global__ __launch_bounds__(256) void wcvt(const float* __restrict__ Wq,
                                            const float* __restrict__ Wk,
                                            const float* __restrict__ Wv,
                                            ushort* __restrict__ Wfm) {
    int g = blockIdx.x * 256 + threadIdx.x;   // 24576 threads
    int n = g >> 7;          // 0..191
    int k8 = g & 127;
    const float* src = (n < 64) ? (Wq + (size_t)n * E_DIM)
                     : (n < 128) ? (Wk + (size_t)(n - 64) * E_DIM)
                     : (Wv + (size_t)(n - 128) * E_DIM);
    float sc = (n < 64) ? 0.045084220f : 1.0f;   // (1/32) * (1/ln2)
    float4 a = *(const float4*)(src + k8 * 8);
    float4 b = *(const float4*)(src + k8 * 8 + 4);
    uint4 o;
    o.x = pk2(a.x * sc, a.y * sc); o.y = pk2(a.z * sc, a.w * sc);
    o.z = pk2(b.x * sc, b.y * sc); o.w = pk2(b.z * sc, b.w * sc);
    int s = k8 >> 3, kc = (k8 >> 2) & 1, qd = k8 & 3;
    int nt = n >> 4, lm = n & 15;
    int lane = qd * 16 + lm;
    *(uint4*)(Wfm + (((size_t)(s * 12 + nt) * 2 + kc) * 64 + lane) * 8) = o;
}

// ---------------- kernel 1: QKV projection ----------------------------------
// 32-row blocks, BK=64, 16 steps. 3-deep x pipeline (load s+3 / stage s+1 /
// compute s); lgkm-only in-loop barriers keep global loads in flight.
__global__ __launch_bounds__(256, 3) void qkv(const float* __restrict__ x,
                                              const ushort* __restrict__ Wfm,
                                              ushort* __restrict__ Qfm,
                                              ushort* __restrict__ Kfm,
                                              ushort* __restrict__ Vfm) {
    __shared__ union {
        ushort a[2][32 * 72];                              // staging dbuf (9216 B)
        struct { ushort c[32 * 136]; ushort vt[64 * 40]; } epi;  // epilogue (13824 B)
    } sm;
    const int tid = threadIdx.x;
    const int w = tid >> 6, l = tid & 63;
    const int lm = l & 15, qd = l >> 4;
    const int m0 = blockIdx.x * 32;

    f32x4 acc[2][3];
#pragma unroll
    for (int r2 = 0; r2 < 2; ++r2)
#pragma unroll
        for (int t = 0; t < 3; ++t) acc[r2][t] = (f32x4){0.f, 0.f, 0.f, 0.f};

    const int srow = tid >> 3, kseg = tid & 7;
    const float* xsrc = x + (size_t)(m0 + srow) * E_DIM + kseg * 8;

    // tile 0 -> LDS[0]
    {
        float4 a0 = *(const float4*)xsrc;
        float4 a1 = *(const float4*)(xsrc + 4);
        uint4 u = {pk2(a0.x, a0.y), pk2(a0.z, a0.w), pk2(a1.x, a1.y), pk2(a1.z, a1.w)};
        *(uint4*)(&sm.a[0][srow * 72 + kseg * 8]) = u;
    }
    // tiles 1,2 -> regs (3-deep pipeline)
    float4 xa0 = *(const float4*)(xsrc + 64);
    float4 xa1 = *(const float4*)(xsrc + 68);
    float4 xb0 = *(const float4*)(xsrc + 128);
    float4 xb1 = *(const float4*)(xsrc + 132);
    __syncthreads();

    for (int s = 0; s < 16; ++s) {
        const int cb = s & 1, nb = cb ^ 1;
        float4 xc0 = xa0, xc1 = xa1;
        if (s < 13) {                       // load tile s+3
            xc0 = *(const float4*)(xsrc + (s + 3) * 64);
            xc1 = *(const float4*)(xsrc + (s + 3) * 64 + 4);
        }
        // W frags for this step (global, L2-resident, lane-dense)
        bf16x8 wf[3][2];
#pragma unroll
        for (int t = 0; t < 3; ++t)
#pragma unroll
            for (int kc = 0; kc < 2; ++kc)
                wf[t][kc] = ldfrag(Wfm + (((size_t)(s * 12 + w * 3 + t) * 2 + kc) * 64 + l) * 8);
        // A frags from LDS
        bf16x8 af[2][2];
#pragma unroll
        for (int r2 = 0; r2 < 2; ++r2)
#pragma unroll
            for (int kc = 0; kc < 2; ++kc)
                af[r2][kc] = ldfrag(&sm.a[cb][(r2 * 16 + lm) * 72 + kc * 32 + qd * 8]);
#pragma unroll
        for (int t = 0; t < 3; ++t)
#pragma unroll
            for (int kc = 0; kc < 2; ++kc)
#pragma unroll
                for (int r2 = 0; r2 < 2; ++r2)
                    acc[r2][t] = __builtin_amdgcn_mfma_f32_16x16x32_bf16(af[r2][kc], wf[t][kc], acc[r2][t], 0, 0, 0);
        // stage tile s+1 (regs loaded two full steps ago)
        if (s < 15) {
            uint4 u = {pk2(xa0.x, xa0.y), pk2(xa0.z, xa0.w), pk2(xa1.x, xa1.y), pk2(xa1.z, xa1.w)};
            *(uint4*)(&sm.a[nb][srow * 72 + kseg * 8]) = u;
        }
        xa0 = xb0; xa1 = xb1; xb0 = xc0; xb1 = xc1;
        if (s < 15) barrier_lgkm();
    }
    __syncthreads();

    // epilogue: acc -> LDS transpose -> frag-major dense stores
#pragma unroll
    for (int r2 = 0; r2 < 2; ++r2)
#pragma unroll
        for (int t = 0; t < 3; ++t) {
            int gc = w * 48 + t * 16 + lm;
            int m = r2 * 16 + qd * 4;
#pragma unroll
            for (int rr = 0; rr < 4; ++rr) {
                ushort v = f2bfu(acc[r2][t][rr]);
                if (gc < 128) sm.epi.c[(m + rr) * 136 + gc] = v;
                else          sm.epi.vt[(gc - 128) * 40 + (m + rr)] = v;
            }
        }
    __syncthreads();

    const int g16b = m0 >> 4;
    const int kt64 = m0 >> 6;
    const int tb   = (m0 >> 4) & 3;
    const int kcv  = (m0 >> 5) & 1;
#pragma unroll
    for (int ii = 0; ii < 3; ++ii) {
        int i = w + ii * 4;
        uint4 val;
        ushort* dst;
        if (i < 4) {
            int qt_l = i >> 1, kc = i & 1;
            val = *(const uint4*)(&sm.epi.c[(qt_l * 16 + lm) * 136 + kc * 32 + qd * 8]);
            dst = Qfm + (((size_t)(g16b + qt_l) * 2 + kc) * 64 + l) * 8;
        } else if (i < 8) {
            int j2 = i - 4, t_l = j2 >> 1, kc = j2 & 1;
            val = *(const uint4*)(&sm.epi.c[(t_l * 16 + lm) * 136 + 64 + kc * 32 + qd * 8]);
            dst = Kfm + (((size_t)((kt64 * 4 + tb + t_l) * 2 + kc)) * 64 + l) * 8;
        } else {
            int t = i - 8;
            val = *(const uint4*)(&sm.epi.vt[(t * 16 + lm) * 40 + qd * 8]);
            dst = Vfm + (((size_t)((kt64 * 4 + t) * 2 + kcv)) * 64 + l) * 8;
        }
        *(uint4*)dst = val;
    }
}

// ---------------- kernel 2: causal flash attention, merged pair -------------
// Each wave processes q-tiles jA=pr and jB=255-pr simultaneously, sharing
// every K/V fragment load while both are active (actA). New this round:
// (1) K fragments software-prefetched one iteration ahead (hides L2 latency
//     under emitP/PV at the 2-waves/SIMD occupancy);
// (2) row-sum l computed by MFMA against an all-ones B fragment (reads the
//     same pf fragments PV loads; removes 12 VALU adds/tile-iter + 4 shfls).
__global__ __launch_bounds__(256, 2) void flashm(const ushort* __restrict__ Qfm,
                                                 const ushort* __restrict__ Kfm,
                                                 const ushort* __restrict__ Vfm,
                                                 float* __restrict__ out) {
    __shared__ union {
        ushort plds[4][2][16 * 72];                       // per wave, per tile (18432 B)
        struct { float ro[4][16][68]; float rl[4][16]; } red;  // block reduce (17664 B)
    } sm;
    const int tid = threadIdx.x;
    const int wv = tid >> 6, l = tid & 63;
    const int lm = l & 15, qd = l >> 4;
    const int pr = blockIdx.x;   // 0..127
    const int bt = blockIdx.y;
    const int jA = pr, jB = 255 - pr;
    const int ktdA = jA >> 2, tdA = jA & 3;
    const int ktdB = jB >> 2, tdB = jB & 3;
    ushort* mypA = sm.plds[wv][0];
    ushort* mypB = sm.plds[wv][1];

    const ushort* kbase = Kfm + ((size_t)(bt * 64) * 8) * 512;
    const ushort* vbase = Vfm + ((size_t)(bt * 64) * 8) * 512;

    bf16x8 qA0, qA1, qB0, qB1;
    {
        const ushort* qp = Qfm + ((size_t)(bt * 256 + jA) * 2) * 512 + l * 8;
        qA0 = ldfrag(qp); qA1 = ldfrag(qp + 512);
        const ushort* qq = Qfm + ((size_t)(bt * 256 + jB) * 2) * 512 + l * 8;
        qB0 = ldfrag(qq); qB1 = ldfrag(qq + 512);
    }
    f32x4 oA[4], oB[4];
#pragma unroll
    for (int t = 0; t < 4; ++t) {
        oA[t] = (f32x4){0.f, 0.f, 0.f, 0.f};
        oB[t] = (f32x4){0.f, 0.f, 0.f, 0.f};
    }
    f32x4 lA = (f32x4){0.f, 0.f, 0.f, 0.f};
    f32x4 lB = (f32x4){0.f, 0.f, 0.f, 0.f};
    const bf16x8 ones = __builtin_bit_cast(bf16x8,
        (uint4){0x3F803F80u, 0x3F803F80u, 0x3F803F80u, 0x3F803F80u});

    // P emission: exp2 + pack to LDS; diag => causal subtile masking
    auto emitP = [&](const f32x4* sf, ushort* wp, bool diag, int td) {
#pragma unroll
        for (int t = 0; t < 4; ++t) {
            if (!diag || t < td) {
                float p0 = ex2(sf[t][0]), p1 = ex2(sf[t][1]);
                float p2 = ex2(sf[t][2]), p3 = ex2(sf[t][3]);
                *(uint2*)(wp + t * 16) = uint2{pk2(p0, p1), pk2(p2, p3)};
            } else if (t == td) {
                float p[4];
#pragma unroll
                for (int rr = 0; rr < 4; ++rr) {
                    float pe = ex2(sf[t][rr]);
                    if (qd * 4 + rr > lm) pe = 0.f;
                    p[rr] = pe;
                }
                *(uint2*)(wp + t * 16) = uint2{pk2(p[0], p[1]), pk2(p[2], p[3])};
            } else {
                *(uint2*)(wp + t * 16) = uint2{0u, 0u};
            }
        }
    };
    // PV + l accumulation (l = P . ones via MFMA, same pf frags as PV)
    auto pv = [&](const ushort* myp, const uint4 (&vu)[4][2], f32x4* o, f32x4& lac) {
        bf16x8 p0 = ldfrag(myp + lm * 72 + qd * 8);
        bf16x8 p1 = ldfrag(myp + lm * 72 + 32 + qd * 8);
#pragma unroll
        for (int t = 0; t < 4; ++t) {
            bf16x8 v0 = __builtin_bit_cast(bf16x8, vu[t][0]);
            bf16x8 v1 = __builtin_bit_cast(bf16x8, vu[t][1]);
            o[t] = __builtin_amdgcn_mfma_f32_16x16x32_bf16(p0, v0, o[t], 0, 0, 0);
            o[t] = __builtin_amdgcn_mfma_f32_16x16x32_bf16(p1, v1, o[t], 0, 0, 0);
        }
        lac = __builtin_amdgcn_mfma_f32_16x16x32_bf16(p0, ones, lac, 0, 0, 0);
        lac = __builtin_amdgcn_mfma_f32_16x16x32_bf16(p1, ones, lac, 0, 0, 0);
    };

    // prefetch K for first iteration (kt = wv; wv <= 3 < 32 <= ktdB always)
    uint4 ku[8];
    {
        const ushort* kb = kbase + (size_t)wv * 8 * 512;
#pragma unroll
        for (int i = 0; i < 8; ++i) ku[i] = *(const uint4*)(kb + i * 512 + l * 8);
    }

#pragma unroll 1
    for (int kt = wv; kt <= ktdB; kt += 4) {
        const bool actA = (kt <= ktdA);          // wave-uniform
        const ushort* vb = vbase + (size_t)kt * 8 * 512;
        // V loads for this iteration (consumed after emitP; latency hidden)
        uint4 vu[4][2];
#pragma unroll
        for (int t = 0; t < 4; ++t) {
            vu[t][0] = *(const uint4*)(vb + (t * 2 + 0) * 512 + l * 8);
            vu[t][1] = *(const uint4*)(vb + (t * 2 + 1) * 512 + l * 8);
        }
        // QK^T from prefetched K regs
        f32x4 sfA[4], sfB[4];
#pragma unroll
        for (int t = 0; t < 4; ++t) {
            sfA[t] = (f32x4){0.f, 0.f, 0.f, 0.f};
            sfB[t] = (f32x4){0.f, 0.f, 0.f, 0.f};
        }
#pragma unroll
        for (int t = 0; t < 4; ++t) {
            bf16x8 k0 = __builtin_bit_cast(bf16x8, ku[t * 2 + 0]);
            bf16x8 k1 = __builtin_bit_cast(bf16x8, ku[t * 2 + 1]);
            sfB[t] = __builtin_amdgcn_mfma_f32_16x16x32_bf16(k0, qB0, sfB[t], 0, 0, 0);
            sfB[t] = __builtin_amdgcn_mfma_f32_16x16x32_bf16(k1, qB1, sfB[t], 0, 0, 0);
            if (actA) {
                sfA[t] = __builtin_amdgcn_mfma_f32_16x16x32_bf16(k0, qA0, sfA[t], 0, 0, 0);
                sfA[t] = __builtin_amdgcn_mfma_f32_16x16x32_bf16(k1, qA1, sfA[t], 0, 0, 0);
            }
        }
        // prefetch next iteration's K (hidden under emitP VALU + PV MFMA)
        if (kt + 4 <= ktdB) {
            const ushort* kb = kbase + (size_t)(kt + 4) * 8 * 512;
#pragma unroll
            for (int i = 0; i < 8; ++i) ku[i] = *(const uint4*)(kb + i * 512 + l * 8);
        }
        // softmax P -> LDS (bf16), wave-private
        emitP(sfB, mypB + lm * 72 + qd * 4, kt == ktdB, tdB);
        if (actA) emitP(sfA, mypA + lm * 72 + qd * 4, kt == ktdA, tdA);
        __builtin_amdgcn_wave_barrier();
        __builtin_amdgcn_s_waitcnt(0xC07F);  // lgkmcnt(0): P committed (wave-private)
        __builtin_amdgcn_wave_barrier();
        pv(mypB, vu, oB, lB);
        if (actA) pv(mypA, vu, oA, lA);
        __builtin_amdgcn_wave_barrier();     // next iter's P writes stay after reads
    }

    __syncthreads();   // all waves done with plds -> safe to reuse as red
    // ---- tile A block-reduce + store ----
    // lA[rr] = l[q = qd*4+rr] (replicated across lm); lane lm==0 writes
    if (lm == 0) {
#pragma unroll
        for (int rr = 0; rr < 4; ++rr) sm.red.rl[wv][qd * 4 + rr] = lA[rr];
    }
#pragma unroll
    for (int t = 0; t < 4; ++t)
#pragma unroll
        for (int rr = 0; rr < 4; ++rr)
            sm.red.ro[wv][qd * 4 + rr][t * 16 + lm] = oA[t][rr];
    __syncthreads();
    {
        const int row = wv * 4 + qd;
        float ls = sm.red.rl[0][row] + sm.red.rl[1][row] + sm.red.rl[2][row] + sm.red.rl[3][row];
        float inv = 1.0f / ls;
        float4 s0 = *(const float4*)&sm.red.ro[0][row][lm * 4];
        float4 s1 = *(const float4*)&sm.red.ro[1][row][lm * 4];
        float4 s2 = *(const float4*)&sm.red.ro[2][row][lm * 4];
        float4 s3 = *(const float4*)&sm.red.ro[3][row][lm * 4];
        float4 ov;
        ov.x = (s0.x + s1.x + s2.x + s3.x) * inv;
        ov.y = (s0.y + s1.y + s2.y + s3.y) * inv;
        ov.z = (s0.z + s1.z + s2.z + s3.z) * inv;
        ov.w = (s0.w + s1.w + s2.w + s3.w) * inv;
        *(float4*)(out + ((size_t)bt * T_SEQ + jA * 16 + row) * 64 + lm * 4) = ov;
    }
    __syncthreads();
    // ---- tile B block-reduce + store ----
    if (lm == 0) {
#pragma unroll
        for (int rr = 0; rr < 4; ++rr) sm.red.rl[wv][qd * 4 + rr] = lB[rr];
    }
#pragma unroll
    for (int t = 0; t < 4; ++t)
#pragma unroll
        for (int rr = 0; rr < 4; ++rr)
            sm.red.ro[wv][qd * 4 + rr][t * 16 + lm] = oB[t][rr];
    __syncthreads();
    {
        const int row = wv * 4 + qd;
        float ls = sm.red.rl[0][row] + sm.red.rl[1][row] + sm.red.rl[2][row] + sm.red.rl[3][row];
        float inv = 1.0f / ls;
        float4 s0 = *(const float4*)&sm.red.ro[0][row][lm * 4];
        float4 s1 = *(const float4*)&sm.red.ro[1][row][lm * 4];
        float4 s2 = *(const float4*)&sm.red.ro[2][row][lm * 4];
        float4 s3 = *(const float4*)&sm.red.ro[3][row][lm * 4];
        float4 ov;
        ov.x = (s0.x + s1.x + s2.x + s3.x) * inv;
        ov.y = (s0.y + s1.y + s2.y + s3.y) * inv;
        ov.z = (s0.z + s1.z + s2.z + s3.z) * inv;
        ov.w = (s0.w + s1.w + s2.w + s3.w) * inv;
        *(float4*)(out + ((size_t)bt * T_SEQ + jB * 16 + row) * 64 + lm * 4) = ov;
    }
}

extern "C" void kernel_launch(void* const* d_in, const int* in_sizes, int n_in,
                              void* d_out, int out_size, void* d_ws, size_t ws_size,
                              hipStream_t stream) {
    const float* x  = (const float*)d_in[0];
    const float* Wq = (const float*)d_in[1];
    const float* Wk = (const float*)d_in[2];
    const float* Wv = (const float*)d_in[3];
    float* out = (float*)d_out;

    char* ws = (char*)d_ws;
    ushort* Wfm = (ushort*)(ws);                 // 384 KB
    ushort* Qfm = (ushort*)(ws + 393216);        // 2 MB
    ushort* Kfm = (ushort*)(ws + 2490368);       // 2 MB
    ushort* Vfm = (ushort*)(ws + 4587520);       // 2 MB

    wcvt<<<96, 256, 0, stream>>>(Wq, Wk, Wv, Wfm);
    qkv<<<512, 256, 0, stream>>>(x, Wfm, Qfm, Kfm, Vfm);
    flashm<<<dim3(128, B_BAT), 256, 0, stream>>>(Qfm, Kfm, Vfm, out);
}